// Round 11
// baseline (226.436 us; speedup 1.0000x reference)
//
#include <hip/hip_runtime.h>
#include <hip/hip_bf16.h>
#include <stdint.h>

#define DEVINL __device__ __forceinline__

using bf16x8 = __attribute__((ext_vector_type(8))) short;
using f32x4  = __attribute__((ext_vector_type(4))) float;

static constexpr int NPTS = 50000;
static constexpr int NPAD = 50176;         // 196 * 256
static constexpr int DIM  = 768;
static constexpr int DATT = 128;
static constexpr int NRB  = NPAD / 128;    // 392 row blocks (gate)

DEVINL ushort f2b(float f) {               // RNE float->bf16 (finite inputs)
  uint32_t u = __float_as_uint(f);
  u += 0x7fffu + ((u >> 16) & 1u);
  return (ushort)(u >> 16);
}
DEVINL float b2f(ushort u) { return __uint_as_float(((uint32_t)u) << 16); }

DEVINL void gload_lds16(const void* g, void* l) {
  __builtin_amdgcn_global_load_lds((const __attribute__((address_space(1))) void*)g,
                                   (__attribute__((address_space(3))) void*)l,
                                   16, 0, 0);
}

// ---------------- K0: merged fp32->bf16 converts (block-range split) ----------
// blocks [0,2048): x (grid-stride, zero-padded); blocks [2048,2432): weights.
__global__ void cvt_merged_kernel(const float* __restrict__ x, const float* __restrict__ Wf,
                                  const float* __restrict__ Wa, const float* __restrict__ Wb,
                                  ushort* __restrict__ xb, ushort* __restrict__ wfb,
                                  ushort* __restrict__ wab, ushort* __restrict__ wbb) {
  if (blockIdx.x < 2048) {
    const int n8_src = NPTS * DIM / 8, n8_dst = NPAD * DIM / 8;
    const int stride = 2048 * 256;
    for (int i = blockIdx.x * 256 + threadIdx.x; i < n8_dst; i += stride) {
      float4 v0 = {0.f, 0.f, 0.f, 0.f}, v1 = {0.f, 0.f, 0.f, 0.f};
      if (i < n8_src) {
        const float4* s4 = (const float4*)x;
        v0 = s4[(long)i * 2];
        v1 = s4[(long)i * 2 + 1];
      }
      ushort4 o0 = { f2b(v0.x), f2b(v0.y), f2b(v0.z), f2b(v0.w) };
      ushort4 o1 = { f2b(v1.x), f2b(v1.y), f2b(v1.z), f2b(v1.w) };
      ((ushort4*)xb)[(long)i * 2]     = o0;
      ((ushort4*)xb)[(long)i * 2 + 1] = o1;
    }
  } else {
    const int NF = DIM * DIM / 8, NA = DATT * DIM / 8;
    const int i = (blockIdx.x - 2048) * 256 + threadIdx.x;
    const float* src; ushort* dst; int j;
    if (i < NF)               { src = Wf; dst = wfb; j = i; }
    else if (i < NF + NA)     { src = Wa; dst = wab; j = i - NF; }
    else if (i < NF + 2 * NA) { src = Wb; dst = wbb; j = i - NF - NA; }
    else return;
    const float4* s4 = (const float4*)src;
    float4 v0 = s4[(long)j * 2];
    float4 v1 = s4[(long)j * 2 + 1];
    ushort4 o0 = { f2b(v0.x), f2b(v0.y), f2b(v0.z), f2b(v0.w) };
    ushort4 o1 = { f2b(v1.x), f2b(v1.y), f2b(v1.z), f2b(v1.w) };
    ((ushort4*)dst)[(long)j * 2]     = o0;
    ((ushort4*)dst)[(long)j * 2 + 1] = o1;
  }
}

// ---------------- K1: h = relu(x @ Wf^T + bias) — R8 kernel verbatim (87.5us) -
__global__ __launch_bounds__(512)
void gemm_h_kernel(const ushort* __restrict__ A, const ushort* __restrict__ B,
                   const float* __restrict__ bias, ushort* __restrict__ H) {
  __shared__ ushort lds[3][24576];   // per buf: A[256][64] @0, B[128][64] @16384

  const int tid  = threadIdx.x;
  const int wid  = tid >> 6;           // 0..7
  const int lane = tid & 63;

  const int bid  = blockIdx.x;                       // 0..1175
  const int wgid = (bid & 7) * 147 + (bid >> 3);     // chunked XCD swizzle (1176%8==0)
  const int row0 = (wgid / 6) * 256;
  const int col0 = (wgid % 6) * 128;

  const int wrow = (wid >> 1) * 64;    // 0,64,128,192
  const int wcol = (wid & 1) * 64;     // 0,64

  const int srow = lane >> 3;                          // 0..7
  const int scol = ((lane & 7) ^ (lane >> 3)) * 8;     // pre-swizzled src col-chunk

  const ushort* Abase = A + (long)row0 * DIM;
  const ushort* Bbase = B + (long)col0 * DIM;

  auto STAGE_A = [&](int t, int buf) {   // 4 gload_lds per thread (32KB)
    const int k0 = t * 64;
#pragma unroll
    for (int i = 0; i < 4; ++i) {
      const int ch = i * 8 + wid;                      // 0..31 (8 rows each)
      gload_lds16(Abase + (long)(ch * 8 + srow) * DIM + k0 + scol,
                  &lds[buf][ch * 512]);
    }
  };
  auto STAGE_B = [&](int t, int buf) {   // 2 gload_lds per thread (16KB)
    const int k0 = t * 64;
#pragma unroll
    for (int i = 0; i < 2; ++i) {
      const int ch = i * 8 + wid;                      // 0..15
      gload_lds16(Bbase + (long)(ch * 8 + srow) * DIM + k0 + scol,
                  &lds[buf][16384 + ch * 512]);
    }
  };

  f32x4 acc[4][4] = {};

  STAGE_A(0, 0); STAGE_B(0, 0);
  STAGE_A(1, 1); STAGE_B(1, 1);
  asm volatile("s_waitcnt vmcnt(6)" ::: "memory");     // tile 0 landed; tile 1 in flight
  __builtin_amdgcn_s_barrier();

  int c = 0;
#pragma unroll 1
  for (int t = 0; t < 12; ++t) {
    const int nb = (c == 0) ? 2 : c - 1;               // (t+2)%3
    const ushort* Ab = &lds[c][0];
    const ushort* Bb = &lds[c][16384];

    // ================= phase 0 : kk=0 =================
    {
      const int j = lane >> 4;                         // k-chunk 0..3
      bf16x8 a[4], b[4];
#pragma unroll
      for (int m = 0; m < 4; ++m) {
        const int ra = wrow + m * 16 + (lane & 15);
        a[m] = *(const bf16x8*)(Ab + ra * 64 + ((j ^ (ra & 7)) << 3));
      }
#pragma unroll
      for (int n = 0; n < 4; ++n) {
        const int rb = wcol + n * 16 + (lane & 15);
        b[n] = *(const bf16x8*)(Bb + rb * 64 + ((j ^ (rb & 7)) << 3));
      }
      if (t < 10) STAGE_A(t + 2, nb);                  // prefetch half 1 of tile t+2
      __builtin_amdgcn_s_barrier();
      asm volatile("s_waitcnt lgkmcnt(0)" ::: "memory");
      __builtin_amdgcn_sched_barrier(0);
      __builtin_amdgcn_s_setprio(1);
#pragma unroll
      for (int n = 0; n < 4; ++n)
#pragma unroll
        for (int m = 0; m < 4; ++m)
          acc[m][n] = __builtin_amdgcn_mfma_f32_16x16x32_bf16(a[m], b[n], acc[m][n], 0, 0, 0);
      __builtin_amdgcn_s_setprio(0);
      __builtin_amdgcn_sched_barrier(0);
      __builtin_amdgcn_s_barrier();
    }
    // ================= phase 1 : kk=1 =================
    {
      const int j = 4 + (lane >> 4);                   // k-chunk 4..7
      bf16x8 a[4], b[4];
#pragma unroll
      for (int m = 0; m < 4; ++m) {
        const int ra = wrow + m * 16 + (lane & 15);
        a[m] = *(const bf16x8*)(Ab + ra * 64 + ((j ^ (ra & 7)) << 3));
      }
#pragma unroll
      for (int n = 0; n < 4; ++n) {
        const int rb = wcol + n * 16 + (lane & 15);
        b[n] = *(const bf16x8*)(Bb + rb * 64 + ((j ^ (rb & 7)) << 3));
      }
      if (t < 10) STAGE_B(t + 2, nb);                  // prefetch half 2 of tile t+2
      if (t < 10) {
        asm volatile("s_waitcnt vmcnt(6)" ::: "memory"); // t+1 landed; t+2 in flight
      } else if (t == 10) {
        asm volatile("s_waitcnt vmcnt(0)" ::: "memory"); // drain tile 11
      }
      __builtin_amdgcn_s_barrier();
      asm volatile("s_waitcnt lgkmcnt(0)" ::: "memory");
      __builtin_amdgcn_sched_barrier(0);
      __builtin_amdgcn_s_setprio(1);
#pragma unroll
      for (int n = 0; n < 4; ++n)
#pragma unroll
        for (int m = 0; m < 4; ++m)
          acc[m][n] = __builtin_amdgcn_mfma_f32_16x16x32_bf16(a[m], b[n], acc[m][n], 0, 0, 0);
      __builtin_amdgcn_s_setprio(0);
      __builtin_amdgcn_sched_barrier(0);
      __builtin_amdgcn_s_barrier();
    }
    c = (c == 2) ? 0 : c + 1;
  }

  const int lq = lane >> 4;
  const int lc = lane & 15;
#pragma unroll
  for (int n = 0; n < 4; ++n) {
    const int cg = col0 + wcol + n * 16 + lc;
    const float bv = bias[cg];
#pragma unroll
    for (int m = 0; m < 4; ++m) {
      const int rg = row0 + wrow + m * 16 + lq * 4;
#pragma unroll
      for (int r2 = 0; r2 < 4; ++r2) {
        float v = acc[m][n][r2] + bv;
        v = fmaxf(v, 0.0f);
        H[(long)(rg + r2) * DIM + cg] = f2b(v);
      }
    }
  }
}

// ---------------- K2: FUSED gate + block softmax + weighted partial -----------
// Phase A (= proven gate): logits for 128 rows -> LDS.
// Phase B: block-local m_b = max l, w = exp(l - m_b) (0 for padded rows),
//          S_b = sum w -> part2[b] = (m_b, S_b).
// Phase C: part[b][d] = sum_r w[r] * h[row0+r][d] (h rows are L2-hot: this
//          block just streamed them). Per wave: its own 16 rows x 768 cols;
//          cross-wave reduce through LDS. All trees fixed-order/deterministic.
__global__ __launch_bounds__(512)
void gate_fused_kernel(const ushort* __restrict__ Hm, const ushort* __restrict__ Wa,
                       const ushort* __restrict__ Wb, const float* __restrict__ Wc,
                       float* __restrict__ part2, float* __restrict__ part) {
  __shared__ ushort Hs [128 * 64];
  __shared__ ushort Was[128 * 64];
  __shared__ ushort Wbs[128 * 64];
  __shared__ float  l_lds[128];
  __shared__ float  w_lds[128];
  __shared__ float  mb_lds;
  __shared__ float  lds_part[8 * 768];   // 24KB
  const int tid  = threadIdx.x;
  const int wid  = tid >> 6;           // 0..7
  const int lane = tid & 63;
  const int row0 = blockIdx.x * 128;

  f32x4 fa[8] = {};
  f32x4 fb[8] = {};

  const int ld_r = lane >> 3;
  const int ld_c = (lane & 7) * 8;

  for (int k0 = 0; k0 < DIM; k0 += 64) {
    __syncthreads();
#pragma unroll
    for (int i = 0; i < 2; ++i) {
      const int ch = i * 8 + wid;      // 0..15
      const int r  = ch * 8 + ld_r;    // 0..127
      gload_lds16(Hm + (long)(row0 + r) * DIM + k0 + ld_c, Hs  + ch * 512);
      gload_lds16(Wa + (long)r * DIM        + k0 + ld_c, Was + ch * 512);
      gload_lds16(Wb + (long)r * DIM        + k0 + ld_c, Wbs + ch * 512);
    }
    __syncthreads();
#pragma unroll
    for (int kk = 0; kk < 2; ++kk) {
      const int kc = kk * 32 + (lane >> 4) * 8;
      bf16x8 h = *(const bf16x8*)(Hs + (wid * 16 + (lane & 15)) * 64 + kc);
#pragma unroll
      for (int n = 0; n < 8; ++n) {
        bf16x8 wa = *(const bf16x8*)(Was + (n * 16 + (lane & 15)) * 64 + kc);
        bf16x8 wb = *(const bf16x8*)(Wbs + (n * 16 + (lane & 15)) * 64 + kc);
        fa[n] = __builtin_amdgcn_mfma_f32_16x16x32_bf16(h, wa, fa[n], 0, 0, 0);
        fb[n] = __builtin_amdgcn_mfma_f32_16x16x32_bf16(h, wb, fb[n], 0, 0, 0);
      }
    }
  }

  {
    const int lc = lane & 15;
    const int lq = lane >> 4;
    float g[4];
#pragma unroll
    for (int r = 0; r < 4; ++r) {
      float s = 0.f;
#pragma unroll
      for (int n = 0; n < 8; ++n) {
        float av = fmaxf(fa[n][r], 0.f);
        float sg = 1.f / (1.f + expf(-fb[n][r]));
        s += av * sg * Wc[n * 16 + lc];
      }
      s += __shfl_xor(s, 1);
      s += __shfl_xor(s, 2);
      s += __shfl_xor(s, 4);
      s += __shfl_xor(s, 8);
      g[r] = s;
    }
    if (lc == 0) {
#pragma unroll
      for (int r = 0; r < 4; ++r) l_lds[wid * 16 + lq * 4 + r] = g[r];
    }
  }
  __syncthreads();

  // ---- phase B: block-local softmax stats (wave 0 reduces) ----
  if (tid < 64) {
    float a0 = (row0 + tid      < NPTS) ? l_lds[tid]      : -1e30f;
    float a1 = (row0 + 64 + tid < NPTS) ? l_lds[64 + tid] : -1e30f;
    float m = fmaxf(a0, a1);
    for (int o = 32; o > 0; o >>= 1) m = fmaxf(m, __shfl_xor(m, o));
    if (tid == 0) mb_lds = m;
  }
  __syncthreads();
  const float mb = mb_lds;
  if (tid < 128) {
    const int n = row0 + tid;
    w_lds[tid] = (n < NPTS) ? expf(l_lds[tid] - mb) : 0.f;
  }
  __syncthreads();
  if (tid < 64) {
    float s = w_lds[tid] + w_lds[tid + 64];
    for (int o = 32; o > 0; o >>= 1) s += __shfl_xor(s, o);
    if (tid == 0) { part2[blockIdx.x * 2] = mb; part2[blockIdx.x * 2 + 1] = s; }
  }

  // ---- phase C: weighted partial over this block's 128 rows ----
  float acc[3][4] = {};
#pragma unroll 1
  for (int rr = 0; rr < 16; ++rr) {
    const int r = wid * 16 + rr;
    const float w = w_lds[r];
    const ushort* hp = Hm + (long)(row0 + r) * DIM + lane * 4;
#pragma unroll
    for (int ch = 0; ch < 3; ++ch) {
      ushort4 v = *(const ushort4*)(hp + ch * 256);
      acc[ch][0] += w * b2f(v.x);
      acc[ch][1] += w * b2f(v.y);
      acc[ch][2] += w * b2f(v.z);
      acc[ch][3] += w * b2f(v.w);
    }
  }
  float* lp = lds_part + wid * 768 + lane * 4;
#pragma unroll
  for (int ch = 0; ch < 3; ++ch) {
    float4 o = { acc[ch][0], acc[ch][1], acc[ch][2], acc[ch][3] };
    *(float4*)(lp + ch * 256) = o;
  }
  __syncthreads();
#pragma unroll
  for (int c2 = tid; c2 < 768; c2 += 512) {
    float s = 0.f;
#pragma unroll
    for (int w2 = 0; w2 < 8; ++w2) s += lds_part[w2 * 768 + c2];
    part[(long)blockIdx.x * 768 + c2] = s;
  }
}

// ---------------- K3: global combine stats: M, scale[b], denom ----------------
__global__ __launch_bounds__(512)
void stats2_kernel(const float* __restrict__ part2, float* __restrict__ sden) {
  __shared__ float red[512];
  const int tid = threadIdx.x;
  const float m = (tid < NRB) ? part2[tid * 2] : -1e30f;
  red[tid] = m; __syncthreads();
  for (int s = 256; s > 0; s >>= 1) {
    if (tid < s) red[tid] = fmaxf(red[tid], red[tid + s]);
    __syncthreads();
  }
  const float M = red[0];
  __syncthreads();
  const float scale = (tid < NRB) ? expf(m - M) : 0.f;
  if (tid < NRB) sden[tid] = scale;
  red[tid] = (tid < NRB) ? scale * part2[tid * 2 + 1] : 0.f;
  __syncthreads();
  for (int s = 256; s > 0; s >>= 1) {
    if (tid < s) red[tid] += red[tid + s];
    __syncthreads();
  }
  if (tid == 0) sden[NRB] = red[0];
}

// ---------------- K4: out[d] = (sum_b scale[b]*part[b][d]) / denom ------------
__global__ __launch_bounds__(128)
void final_scaled_kernel(const float* __restrict__ part, const float* __restrict__ sden,
                         float* __restrict__ out) {
  __shared__ float sc[NRB + 1];
  const int tid = threadIdx.x;
  for (int i = tid; i < NRB + 1; i += 128) sc[i] = sden[i];
  __syncthreads();
  const int c = blockIdx.x * 128 + tid;
  float s = 0.f;
#pragma unroll 4
  for (int b = 0; b < NRB; ++b) s += sc[b] * part[(long)b * 768 + c];
  out[c] = s / sc[NRB];
}

extern "C" void kernel_launch(void* const* d_in, const int* in_sizes, int n_in,
                              void* d_out, int out_size, void* d_ws, size_t ws_size,
                              hipStream_t stream) {
  const float* x  = (const float*)d_in[0];
  const float* Wf = (const float*)d_in[1];
  const float* bf = (const float*)d_in[2];
  const float* Wa = (const float*)d_in[3];
  const float* Wb = (const float*)d_in[4];
  const float* Wc = (const float*)d_in[5];
  float* out = (float*)d_out;

  char* p = (char*)d_ws;
  ushort* xb  = (ushort*)p; p += (size_t)NPAD * DIM * 2;   // 77.1 MB
  ushort* hb  = (ushort*)p; p += (size_t)NPAD * DIM * 2;   // 77.1 MB
  ushort* wfb = (ushort*)p; p += (size_t)DIM * DIM * 2;
  ushort* wab = (ushort*)p; p += (size_t)DATT * DIM * 2;
  ushort* wbb = (ushort*)p; p += (size_t)DATT * DIM * 2;
  float* part2 = (float*)p; p += (size_t)NRB * 2 * 4 + 256;
  float* sden  = (float*)p; p += (size_t)(NRB + 1) * 4 + 256;
  float* part  = (float*)p; p += (size_t)NRB * DIM * 4;

  cvt_merged_kernel<<<2432, 256, 0, stream>>>(x, Wf, Wa, Wb, xb, wfb, wab, wbb);

  gemm_h_kernel<<<196 * 6, 512, 0, stream>>>(xb, wfb, bf, hb);
  gate_fused_kernel<<<NRB, 512, 0, stream>>>(hb, wab, wbb, Wc, part2, part);
  stats2_kernel<<<1, 512, 0, stream>>>(part2, sden);
  final_scaled_kernel<<<6, 128, 0, stream>>>(part, sden, out);
}